// Round 1
// baseline (83.983 us; speedup 1.0000x reference)
//
#include <hip/hip_runtime.h>
#include <math.h>

// Problem constants (from reference setup_inputs)
#define B_    32
#define C_    4
#define N_    16384
#define RES_  32

// Main kernel tiling: BPB blocks per batch, TPB threads, PTS points/thread
#define BPB   32
#define TPB   256
#define PTS   (N_ / (BPB * TPB))   // = 2

// Kernel 1: per-(b, point-chunk) block computes sum over its points of
// sum_c || reflected - cp ||, writes one float partial per block to d_ws.
__global__ __launch_bounds__(TPB) void sym_main(
    const float* __restrict__ y_pred,   // (B, C, 4)
    const float* __restrict__ points,   // (B, N, 3)
    const float* __restrict__ cp,       // (B, RES, RES, RES, 3)
    float* __restrict__ partials)       // (B * BPB)
{
  const int b = blockIdx.y;

  // Plane params (uniform across block; L1-broadcast loads)
  const float* yp = y_pred + b * (C_ * 4);
  float nx[C_], ny[C_], nz[C_], dd[C_];
#pragma unroll
  for (int c = 0; c < C_; ++c) {
    float ax = yp[c * 4 + 0];
    float ay = yp[c * 4 + 1];
    float az = yp[c * 4 + 2];
    float inv = 1.0f / sqrtf(ax * ax + ay * ay + az * az);
    nx[c] = ax * inv;
    ny[c] = ay * inv;
    nz[c] = az * inv;
    dd[c] = yp[c * 4 + 3];
  }

  const float* pb  = points + (size_t)b * (N_ * 3);
  const float* cpb = cp + (size_t)b * (RES_ * RES_ * RES_ * 3);

  float acc = 0.0f;
  const int t = blockIdx.x * TPB + threadIdx.x;

#pragma unroll
  for (int k = 0; k < PTS; ++k) {
    const int p = t + k * (BPB * TPB);
    const float px = pb[p * 3 + 0];
    const float py = pb[p * 3 + 1];
    const float pz = pb[p * 3 + 2];
#pragma unroll
    for (int c = 0; c < C_; ++c) {
      float dist = px * nx[c] + py * ny[c] + pz * nz[c] + dd[c];
      float t2 = 2.0f * dist;
      float rx = px - t2 * nx[c];
      float ry = py - t2 * ny[c];
      float rz = pz - t2 * nz[c];
      int vx = (int)fminf(fmaxf(floorf(rx * (float)RES_), 0.0f), (float)(RES_ - 1));
      int vy = (int)fminf(fmaxf(floorf(ry * (float)RES_), 0.0f), (float)(RES_ - 1));
      int vz = (int)fminf(fmaxf(floorf(rz * (float)RES_), 0.0f), (float)(RES_ - 1));
      int idx = ((vx * RES_ + vy) * RES_ + vz) * 3;
      float cx = cpb[idx + 0];
      float cy = cpb[idx + 1];
      float cz = cpb[idx + 2];
      float dx = rx - cx;
      float dy = ry - cy;
      float dz = rz - cz;
      acc += sqrtf(dx * dx + dy * dy + dz * dz);
    }
  }

  // Wave (64-lane) shuffle reduction, then cross-wave via LDS
#pragma unroll
  for (int off = 32; off > 0; off >>= 1)
    acc += __shfl_down(acc, off, 64);

  __shared__ float sred[TPB / 64];
  const int lane = threadIdx.x & 63;
  const int wave = threadIdx.x >> 6;
  if (lane == 0) sred[wave] = acc;
  __syncthreads();
  if (threadIdx.x == 0) {
    float tot = 0.0f;
#pragma unroll
    for (int w = 0; w < TPB / 64; ++w) tot += sred[w];
    partials[b * BPB + blockIdx.x] = tot;
  }
}

// Kernel 2: single block. Sums the B*BPB partials (fp64 accumulate for
// precision: raw sum is ~5e6), adds REG_COEF * mean_b(reg_loss[b]).
__global__ __launch_bounds__(256) void sym_final(
    const float* __restrict__ y_pred,
    const float* __restrict__ partials,
    float* __restrict__ out)
{
  __shared__ double sd[256];
  double acc = 0.0;
  for (int i = threadIdx.x; i < B_ * BPB; i += 256)
    acc += (double)partials[i];
  acc *= (1.0 / (double)N_);   // mean over n folded into the b,c sum

  if (threadIdx.x < B_) {
    const int b = threadIdx.x;
    const float* yp = y_pred + b * (C_ * 4);
    float nh[C_][3];
#pragma unroll
    for (int c = 0; c < C_; ++c) {
      float ax = yp[c * 4 + 0];
      float ay = yp[c * 4 + 1];
      float az = yp[c * 4 + 2];
      float inv = 1.0f / sqrtf(ax * ax + ay * ay + az * az);
      nh[c][0] = ax * inv;
      nh[c][1] = ay * inv;
      nh[c][2] = az * inv;
    }
    float s = 0.0f;
#pragma unroll
    for (int c = 0; c < C_; ++c) {
#pragma unroll
      for (int e = 0; e < C_; ++e) {
        float dot = nh[c][0] * nh[e][0] + nh[c][1] * nh[e][1] + nh[c][2] * nh[e][2];
        float g = dot - ((c == e) ? 1.0f : 0.0f);
        s += g * g;
      }
    }
    acc += (25.0 / (double)B_) * (double)sqrtf(s);
  }

  sd[threadIdx.x] = acc;
  __syncthreads();
  for (int off = 128; off > 0; off >>= 1) {
    if (threadIdx.x < off) sd[threadIdx.x] += sd[threadIdx.x + off];
    __syncthreads();
  }
  if (threadIdx.x == 0) out[0] = (float)sd[0];
}

extern "C" void kernel_launch(void* const* d_in, const int* in_sizes, int n_in,
                              void* d_out, int out_size, void* d_ws, size_t ws_size,
                              hipStream_t stream) {
  const float* y_pred = (const float*)d_in[0];   // (32,4,4)
  const float* points = (const float*)d_in[1];   // (32,16384,3)
  // d_in[2] = voxel_grid — unused by the reference loss
  const float* cp     = (const float*)d_in[3];   // (32,32,32,32,3)
  float* partials = (float*)d_ws;                // B_*BPB floats
  float* out = (float*)d_out;

  sym_main<<<dim3(BPB, B_), TPB, 0, stream>>>(y_pred, points, cp, partials);
  sym_final<<<1, 256, 0, stream>>>(y_pred, partials, out);
}

// Round 2
// 81.374 us; speedup vs baseline: 1.0321x; 1.0321x over previous
//
#include <hip/hip_runtime.h>
#include <math.h>

// Problem constants (from reference setup_inputs)
#define B_    32
#define C_    4
#define N_    16384
#define RES_  32

// Main kernel tiling: CHUNKS blocks per batch, TPB threads, PTS points/thread
#define CHUNKS 32
#define TPB    256
#define PTS    (N_ / (CHUNKS * TPB))   // = 2
#define NGATH  (PTS * C_)              // 8 gathers per thread

// Kernel 1: grid = 1024 1D blocks, XCD-swizzled so each XCD (id%8 assumed)
// serves exactly 4 batches -> per-XCD gather working set 4*393KB = 1.6MB < 4MiB L2.
__global__ __launch_bounds__(TPB) void sym_main(
    const float* __restrict__ y_pred,   // (B, C, 4)
    const float* __restrict__ points,   // (B, N, 3)
    const float* __restrict__ cp,       // (B, RES, RES, RES, 3)
    float* __restrict__ partials)       // (B * CHUNKS)
{
  // XCD-aware decomposition of linear block id:
  //   xcd  = id % 8   (assumed hardware round-robin XCD assignment)
  //   b    = xcd + 8 * (slot % 4)   -> 4 distinct batches per XCD
  //   chunk= slot / 4               -> 32 point-chunks per batch
  const int id   = blockIdx.x;
  const int xcd  = id & 7;
  const int slot = id >> 3;
  const int b     = xcd + 8 * (slot & 3);
  const int chunk = slot >> 2;

  // Plane params (uniform across block; scalar-cached loads)
  const float* yp = y_pred + b * (C_ * 4);
  float nx[C_], ny[C_], nz[C_], dd[C_];
#pragma unroll
  for (int c = 0; c < C_; ++c) {
    float ax = yp[c * 4 + 0];
    float ay = yp[c * 4 + 1];
    float az = yp[c * 4 + 2];
    float inv = 1.0f / sqrtf(ax * ax + ay * ay + az * az);
    nx[c] = ax * inv;
    ny[c] = ay * inv;
    nz[c] = az * inv;
    dd[c] = yp[c * 4 + 3];
  }

  const float* pb  = points + (size_t)b * (N_ * 3);
  const float* cpb = cp + (size_t)b * (RES_ * RES_ * RES_ * 3);

  const int t = chunk * TPB + threadIdx.x;

  // Phase 1: load points, compute all reflected vectors + gather indices.
  float rx[NGATH], ry[NGATH], rz[NGATH];
  int lin[NGATH];
#pragma unroll
  for (int k = 0; k < PTS; ++k) {
    const int p = t + k * (CHUNKS * TPB);
    const float px = pb[p * 3 + 0];
    const float py = pb[p * 3 + 1];
    const float pz = pb[p * 3 + 2];
#pragma unroll
    for (int c = 0; c < C_; ++c) {
      const int g = k * C_ + c;
      float dist = px * nx[c] + py * ny[c] + pz * nz[c] + dd[c];
      float t2 = 2.0f * dist;
      float x = px - t2 * nx[c];
      float y = py - t2 * ny[c];
      float z = pz - t2 * nz[c];
      rx[g] = x; ry[g] = y; rz[g] = z;
      int vx = (int)fminf(fmaxf(floorf(x * (float)RES_), 0.0f), (float)(RES_ - 1));
      int vy = (int)fminf(fmaxf(floorf(y * (float)RES_), 0.0f), (float)(RES_ - 1));
      int vz = (int)fminf(fmaxf(floorf(z * (float)RES_), 0.0f), (float)(RES_ - 1));
      lin[g] = ((vx * RES_ + vy) * RES_ + vz) * 3;
    }
  }

  // Phase 2: issue all 8 gathers (12B float3 -> global_load_dwordx3 each),
  // all outstanding simultaneously to hide L2 latency.
  float cx[NGATH], cy[NGATH], cz[NGATH];
#pragma unroll
  for (int g = 0; g < NGATH; ++g) {
    cx[g] = cpb[lin[g] + 0];
    cy[g] = cpb[lin[g] + 1];
    cz[g] = cpb[lin[g] + 2];
  }

  // Phase 3: distances into 4 independent accumulators (break sqrt chain).
  float a0 = 0.0f, a1 = 0.0f, a2 = 0.0f, a3 = 0.0f;
#pragma unroll
  for (int g = 0; g < NGATH; g += 4) {
    float dx0 = rx[g+0] - cx[g+0], dy0 = ry[g+0] - cy[g+0], dz0 = rz[g+0] - cz[g+0];
    float dx1 = rx[g+1] - cx[g+1], dy1 = ry[g+1] - cy[g+1], dz1 = rz[g+1] - cz[g+1];
    float dx2 = rx[g+2] - cx[g+2], dy2 = ry[g+2] - cy[g+2], dz2 = rz[g+2] - cz[g+2];
    float dx3 = rx[g+3] - cx[g+3], dy3 = ry[g+3] - cy[g+3], dz3 = rz[g+3] - cz[g+3];
    a0 += sqrtf(dx0 * dx0 + dy0 * dy0 + dz0 * dz0);
    a1 += sqrtf(dx1 * dx1 + dy1 * dy1 + dz1 * dz1);
    a2 += sqrtf(dx2 * dx2 + dy2 * dy2 + dz2 * dz2);
    a3 += sqrtf(dx3 * dx3 + dy3 * dy3 + dz3 * dz3);
  }
  float acc = (a0 + a1) + (a2 + a3);

  // Wave (64-lane) shuffle reduction, then cross-wave via LDS
#pragma unroll
  for (int off = 32; off > 0; off >>= 1)
    acc += __shfl_down(acc, off, 64);

  __shared__ float sred[TPB / 64];
  const int lane = threadIdx.x & 63;
  const int wave = threadIdx.x >> 6;
  if (lane == 0) sred[wave] = acc;
  __syncthreads();
  if (threadIdx.x == 0) {
    float tot = 0.0f;
#pragma unroll
    for (int w = 0; w < TPB / 64; ++w) tot += sred[w];
    partials[b * CHUNKS + chunk] = tot;
  }
}

// Kernel 2: single block. Sums the B*CHUNKS partials (fp64 accumulate for
// precision: raw sum is ~5e6), adds REG_COEF * mean_b(reg_loss[b]).
__global__ __launch_bounds__(256) void sym_final(
    const float* __restrict__ y_pred,
    const float* __restrict__ partials,
    float* __restrict__ out)
{
  __shared__ double sd[256];
  double acc = 0.0;
  for (int i = threadIdx.x; i < B_ * CHUNKS; i += 256)
    acc += (double)partials[i];
  acc *= (1.0 / (double)N_);   // mean over n folded into the b,c sum

  if (threadIdx.x < B_) {
    const int b = threadIdx.x;
    const float* yp = y_pred + b * (C_ * 4);
    float nh[C_][3];
#pragma unroll
    for (int c = 0; c < C_; ++c) {
      float ax = yp[c * 4 + 0];
      float ay = yp[c * 4 + 1];
      float az = yp[c * 4 + 2];
      float inv = 1.0f / sqrtf(ax * ax + ay * ay + az * az);
      nh[c][0] = ax * inv;
      nh[c][1] = ay * inv;
      nh[c][2] = az * inv;
    }
    float s = 0.0f;
#pragma unroll
    for (int c = 0; c < C_; ++c) {
#pragma unroll
      for (int e = 0; e < C_; ++e) {
        float dot = nh[c][0] * nh[e][0] + nh[c][1] * nh[e][1] + nh[c][2] * nh[e][2];
        float g = dot - ((c == e) ? 1.0f : 0.0f);
        s += g * g;
      }
    }
    acc += (25.0 / (double)B_) * (double)sqrtf(s);
  }

  sd[threadIdx.x] = acc;
  __syncthreads();
  for (int off = 128; off > 0; off >>= 1) {
    if (threadIdx.x < off) sd[threadIdx.x] += sd[threadIdx.x + off];
    __syncthreads();
  }
  if (threadIdx.x == 0) out[0] = (float)sd[0];
}

extern "C" void kernel_launch(void* const* d_in, const int* in_sizes, int n_in,
                              void* d_out, int out_size, void* d_ws, size_t ws_size,
                              hipStream_t stream) {
  const float* y_pred = (const float*)d_in[0];   // (32,4,4)
  const float* points = (const float*)d_in[1];   // (32,16384,3)
  // d_in[2] = voxel_grid — unused by the reference loss
  const float* cp     = (const float*)d_in[3];   // (32,32,32,32,3)
  float* partials = (float*)d_ws;                // B_*CHUNKS floats
  float* out = (float*)d_out;

  sym_main<<<B_ * CHUNKS, TPB, 0, stream>>>(y_pred, points, cp, partials);
  sym_final<<<1, 256, 0, stream>>>(y_pred, partials, out);
}